// Round 1
// baseline (1239.259 us; speedup 1.0000x reference)
//
#include <hip/hip_runtime.h>
#include <math.h>

#define BATCH 64
#define SEQ   4096
#define DIM   1024

// 16-float dot fragment: x[0..3] are the lane's four float4s of a row,
// w0..w3 the matching weight fragments.
__device__ __forceinline__ float dot16(const float4* x,
                                       const float4& w0, const float4& w1,
                                       const float4& w2, const float4& w3) {
    return x[0].x*w0.x + x[0].y*w0.y + x[0].z*w0.z + x[0].w*w0.w
         + x[1].x*w1.x + x[1].y*w1.y + x[1].z*w1.z + x[1].w*w1.w
         + x[2].x*w2.x + x[2].y*w2.y + x[2].z*w2.z + x[2].w*w2.w
         + x[3].x*w3.x + x[3].y*w3.y + x[3].z*w3.z + x[3].w*w3.w;
}

// Pass 1: per-(batch, split) online-softmax partial.
// Block = 256 threads = 4 waves. A wave's 64 lanes hold a full D=1024 row:
// lane owns cols {q*256 + lane*4 + j}, q=0..3, j=0..3.
// Waves own interleaved ROW PAIRS (stride 8) of the block's chunk, processed
// through an explicit 2-deep software pipeline (xA/xB double buffer) so the
// next pair's 8 global loads are in flight while the current pair's
// butterfly-reduce/exp/rescale runs.
// launch_bounds(256,3): VGPR cap ~170 — enough headroom that the double
// buffer does NOT spill (the previous (256,4)=128 cap was right at the live
//-register count and blocked cross-iteration prefetch).
__global__ __launch_bounds__(256, 3)
void attn_partial_kernel(const float* __restrict__ inp,
                         const int*   __restrict__ lens,
                         const float* __restrict__ w,
                         float* __restrict__ ws_c,
                         float* __restrict__ ws_m,
                         float* __restrict__ ws_l,
                         int splits)
{
    const int split = blockIdx.x;
    const int b     = blockIdx.y;
    const int t     = threadIdx.x;
    const int wave  = t >> 6;
    const int lane  = t & 63;
    const int colb  = lane * 4;

    __shared__ float c_s[4][DIM];
    __shared__ float m_s[4];
    __shared__ float l_s[4];

    const int len   = lens[b];
    // per-batch balanced chunking: every block gets <= ceil(len/splits) rows
    const int chunk = (len + splits - 1) / splits;
    const int s0    = split * chunk;
    const int s1    = min(s0 + chunk, len);

    // weight fragment (reused every row)
    const float4 w0 = *(const float4*)(w       + colb);
    const float4 w1 = *(const float4*)(w + 256 + colb);
    const float4 w2 = *(const float4*)(w + 512 + colb);
    const float4 w3 = *(const float4*)(w + 768 + colb);

    float  m = -INFINITY, l = 0.0f;
    float4 c[4] = {{0,0,0,0},{0,0,0,0},{0,0,0,0},{0,0,0,0}};

    const float* base = inp + (size_t)b * SEQ * DIM + colb;

    // interleaved pair assignment: wave owns row pairs {r, r+1} for
    // r = s0 + wave*2 + 8k. Exactly covers [s0, s1); at most one leftover
    // single row per wave (when r == s1-1).
    int r = s0 + (wave << 1);
    int pairs = 0;
    if (s1 - r >= 2) pairs = (s1 - r - 2) / 8 + 1;
    const int rs = r + pairs * 8;   // leftover single-row position (if < s1)

    float4 xA[2][4], xB[2][4];

#define LOAD2(X, row_) do {                                                   \
        const float* rp_ = base + (size_t)(row_) * DIM;                       \
        _Pragma("unroll")                                                     \
        for (int j_ = 0; j_ < 2; ++j_)                                        \
            _Pragma("unroll")                                                 \
            for (int q_ = 0; q_ < 4; ++q_)                                    \
                X[j_][q_] = *(const float4*)(rp_ + j_ * DIM + q_ * 256);      \
    } while (0)

#define PROC2(X) do {                                                         \
        float pd0_ = dot16(X[0], w0, w1, w2, w3);                             \
        float pd1_ = dot16(X[1], w0, w1, w2, w3);                             \
        _Pragma("unroll")                                                     \
        for (int off_ = 32; off_ > 0; off_ >>= 1) {                           \
            pd0_ += __shfl_xor(pd0_, off_, 64);                               \
            pd1_ += __shfl_xor(pd1_, off_, 64);                               \
        }                                                                     \
        const float mn_    = fmaxf(m, fmaxf(pd0_, pd1_));                     \
        const float alpha_ = __expf(m - mn_);                                 \
        const float p0_    = __expf(pd0_ - mn_);                              \
        const float p1_    = __expf(pd1_ - mn_);                              \
        l = l * alpha_ + p0_ + p1_;                                           \
        _Pragma("unroll")                                                     \
        for (int q_ = 0; q_ < 4; ++q_) {                                      \
            c[q_].x = c[q_].x*alpha_ + p0_*X[0][q_].x + p1_*X[1][q_].x;       \
            c[q_].y = c[q_].y*alpha_ + p0_*X[0][q_].y + p1_*X[1][q_].y;       \
            c[q_].z = c[q_].z*alpha_ + p0_*X[0][q_].z + p1_*X[1][q_].z;       \
            c[q_].w = c[q_].w*alpha_ + p0_*X[0][q_].w + p1_*X[1][q_].w;       \
        }                                                                     \
        m = mn_;                                                              \
    } while (0)

    // 2-deep software pipeline over this wave's pairs
    if (pairs > 0) LOAD2(xA, r);
    int p = 0;
    for (; p + 2 <= pairs; p += 2) {
        LOAD2(xB, r + 8);                 // prefetch pair p+1
        PROC2(xA);                        // compute pair p
        if (p + 2 < pairs) LOAD2(xA, r + 16);  // prefetch pair p+2
        PROC2(xB);                        // compute pair p+1
        r += 16;
    }
    if (p < pairs) {                      // odd pair count: last pair in xA
        PROC2(xA);
        r += 8;
    }

#undef LOAD2
#undef PROC2

    // leftover single row (at most one per wave)
    if (rs < s1) {
        const float* rp = base + (size_t)rs * DIM;
        const float4 x0 = *(const float4*)(rp);
        const float4 x1 = *(const float4*)(rp + 256);
        const float4 x2 = *(const float4*)(rp + 512);
        const float4 x3 = *(const float4*)(rp + 768);

        float pd = x0.x*w0.x + x0.y*w0.y + x0.z*w0.z + x0.w*w0.w
                 + x1.x*w1.x + x1.y*w1.y + x1.z*w1.z + x1.w*w1.w
                 + x2.x*w2.x + x2.y*w2.y + x2.z*w2.z + x2.w*w2.w
                 + x3.x*w3.x + x3.y*w3.y + x3.z*w3.z + x3.w*w3.w;
        #pragma unroll
        for (int off = 32; off > 0; off >>= 1)
            pd += __shfl_xor(pd, off, 64);

        const float mn    = fmaxf(m, pd);
        const float alpha = __expf(m - mn);
        const float pp    = __expf(pd - mn);
        l = l * alpha + pp;
        c[0].x = c[0].x*alpha + pp*x0.x;  c[0].y = c[0].y*alpha + pp*x0.y;
        c[0].z = c[0].z*alpha + pp*x0.z;  c[0].w = c[0].w*alpha + pp*x0.w;
        c[1].x = c[1].x*alpha + pp*x1.x;  c[1].y = c[1].y*alpha + pp*x1.y;
        c[1].z = c[1].z*alpha + pp*x1.z;  c[1].w = c[1].w*alpha + pp*x1.w;
        c[2].x = c[2].x*alpha + pp*x2.x;  c[2].y = c[2].y*alpha + pp*x2.y;
        c[2].z = c[2].z*alpha + pp*x2.z;  c[2].w = c[2].w*alpha + pp*x2.w;
        c[3].x = c[3].x*alpha + pp*x3.x;  c[3].y = c[3].y*alpha + pp*x3.y;
        c[3].z = c[3].z*alpha + pp*x3.z;  c[3].w = c[3].w*alpha + pp*x3.w;
        m = mn;
    }

    // merge the 4 waves' partials through LDS
    #pragma unroll
    for (int q = 0; q < 4; ++q)
        *(float4*)&c_s[wave][colb + q * 256] = c[q];
    if (lane == 0) { m_s[wave] = m; l_s[wave] = l; }
    __syncthreads();

    const float M = fmaxf(fmaxf(m_s[0], m_s[1]), fmaxf(m_s[2], m_s[3]));
    float sc[4];
    float L = 0.0f;
    #pragma unroll
    for (int iw = 0; iw < 4; ++iw) {
        // all-empty block: every m_s=-inf; guard the NaN from (-inf - -inf)
        sc[iw] = (m_s[iw] == -INFINITY) ? 0.0f : __expf(m_s[iw] - M);
        L += sc[iw] * l_s[iw];
    }

    const int oc = t * 4;
    float4 acc = {0,0,0,0};
    #pragma unroll
    for (int iw = 0; iw < 4; ++iw) {
        const float4 ci = *(const float4*)&c_s[iw][oc];
        acc.x += sc[iw]*ci.x; acc.y += sc[iw]*ci.y;
        acc.z += sc[iw]*ci.z; acc.w += sc[iw]*ci.w;
    }

    const size_t idx = (size_t)b * splits + split;
    *(float4*)(ws_c + idx * DIM + oc) = acc;
    if (t == 0) { ws_m[idx] = M; ws_l[idx] = L; }
}

// Pass 2: combine the per-split partials for each batch.
__global__ __launch_bounds__(256)
void attn_reduce_kernel(const float* __restrict__ ws_c,
                        const float* __restrict__ ws_m,
                        const float* __restrict__ ws_l,
                        float* __restrict__ out, int splits)
{
    const int b  = blockIdx.x;
    const int t  = threadIdx.x;
    const int oc = t * 4;

    const float* mb = ws_m + (size_t)b * splits;
    const float* lb = ws_l + (size_t)b * splits;

    float M = -INFINITY;
    #pragma unroll 8
    for (int i = 0; i < splits; ++i) M = fmaxf(M, mb[i]);
    // len >= 1 guarantees split 0 is non-empty -> M finite.

    float  L   = 0.0f;
    float4 acc = {0,0,0,0};
    #pragma unroll 4
    for (int i = 0; i < splits; ++i) {
        const float mi  = mb[i];
        const float scl = (mi == -INFINITY) ? 0.0f : __expf(mi - M);
        L += scl * lb[i];
        const float4 ci = *(const float4*)(ws_c + ((size_t)b * splits + i) * DIM + oc);
        acc.x += scl*ci.x; acc.y += scl*ci.y;
        acc.z += scl*ci.z; acc.w += scl*ci.w;
    }
    const float inv = 1.0f / L;
    float4 o = { acc.x*inv, acc.y*inv, acc.z*inv, acc.w*inv };
    *(float4*)(out + (size_t)b * DIM + oc) = o;
}

extern "C" void kernel_launch(void* const* d_in, const int* in_sizes, int n_in,
                              void* d_out, int out_size, void* d_ws, size_t ws_size,
                              hipStream_t stream) {
    const float* inp  = (const float*)d_in[0];
    const int*   lens = (const int*)  d_in[1];
    const float* w    = (const float*)d_in[2];
    // d_in[3] (bias) intentionally unused: softmax(x + c) == softmax(x).
    float* out = (float*)d_out;

    int splits = 64;
    while (splits > 1 &&
           (size_t)BATCH * splits * (DIM + 2) * sizeof(float) > ws_size)
        splits >>= 1;

    float* wsf  = (float*)d_ws;
    float* ws_c = wsf;                                   // [B*splits, DIM]
    float* ws_m = wsf + (size_t)BATCH * splits * DIM;    // [B*splits]
    float* ws_l = ws_m + (size_t)BATCH * splits;         // [B*splits]

    attn_partial_kernel<<<dim3(splits, BATCH), 256, 0, stream>>>(
        inp, lens, w, ws_c, ws_m, ws_l, splits);
    attn_reduce_kernel<<<BATCH, 256, 0, stream>>>(ws_c, ws_m, ws_l, out, splits);
}